// Round 4
// baseline (139.847 us; speedup 1.0000x reference)
//
#include <hip/hip_runtime.h>

#define N 8192
#define D 512
#define NB (N / 128)          // 64 row blocks (128 rows)
#define NSB 32                // 32 col superblocks (256 cols)
#define MARGIN 0.3f

typedef __attribute__((ext_vector_type(8))) short bf16x8;   // 8 bf16 = 4 VGPRs
typedef __attribute__((ext_vector_type(4))) float f32x4;    // MFMA accumulator

// round-to-nearest-even fp32 -> bf16
__device__ __forceinline__ unsigned short f2bf(float f) {
    unsigned int u = __float_as_uint(f);
    u += 0x7fffu + ((u >> 16) & 1u);
    return (unsigned short)(u >> 16);
}

// async global->LDS, 16B per lane; LDS dest = wave-uniform base + lane*16.
__device__ __forceinline__ void gload_lds16(const void* g, void* l) {
    __builtin_amdgcn_global_load_lds(
        (const __attribute__((address_space(1))) void*)g,
        (__attribute__((address_space(3))) void*)l,
        16, 0, 0);
}

// Kernel 1: per-row fp32 sum-of-squares (exact) + bf16 cast + counter init.
__global__ void prep_kernel(const float* __restrict__ x,
                            unsigned short* __restrict__ xb,
                            float* __restrict__ sq,
                            int* __restrict__ cnt) {
    if (blockIdx.x == 0 && threadIdx.x == 0) cnt[0] = 0;
    int w = threadIdx.x >> 6, lane = threadIdx.x & 63;
    int row = blockIdx.x * 4 + w;
    const float4* p = (const float4*)(x + (size_t)row * D) + lane * 2;
    float4 v0 = p[0], v1 = p[1];
    float s = v0.x * v0.x + v0.y * v0.y + v0.z * v0.z + v0.w * v0.w
            + v1.x * v1.x + v1.y * v1.y + v1.z * v1.z + v1.w * v1.w;
    bf16x8 pk;
    pk[0] = (short)f2bf(v0.x); pk[1] = (short)f2bf(v0.y);
    pk[2] = (short)f2bf(v0.z); pk[3] = (short)f2bf(v0.w);
    pk[4] = (short)f2bf(v1.x); pk[5] = (short)f2bf(v1.y);
    pk[6] = (short)f2bf(v1.z); pk[7] = (short)f2bf(v1.w);
    *(bf16x8*)(xb + (size_t)row * D + lane * 8) = pk;
    #pragma unroll
    for (int o = 32; o > 0; o >>= 1) s += __shfl_xor(s, o);
    if (lane == 0) sq[row] = s;
}

// Kernel 2: 128x256 brick (A reused across 2 col-tiles), triangular grid over
// (bi rowblock 128, bj2 col-superblock 256): brick exists iff bi <= 2*bj2+1.
// Per wave 64x128 = 4tm x 8tn of 16x16x32 MFMA. Selection in d^2-space.
// Row-side partial -> slot bj2 in apvR[32][N]; col-side -> slot bi in apvC[64][N].
// Both sides always run; max/min idempotence makes diagonal overlap harmless.
__global__ __launch_bounds__(256, 2)
void gemm_kernel(const unsigned short* __restrict__ xb,
                 const float* __restrict__ sq,
                 const int* __restrict__ tgt,
                 float* __restrict__ apvR, float* __restrict__ anvR,
                 float* __restrict__ apvC, float* __restrict__ anvC) {
    __shared__ __align__(16) char smem_raw[49152];          // A(16K)+B(32K); reused
    __shared__ float sqI[128], sqJ[256];
    __shared__ int tI[128], tJ[256];
    unsigned short* Asm = (unsigned short*)smem_raw;        // [128][64] bf16 swizzled
    unsigned short* Bsm = Asm + 128 * 64;                   // [256][64] bf16 swizzled
    float* redAp = (float*)smem_raw;                        // [128][34]
    float* redAn = redAp + 128 * 34;                        // 34816 B
    float* colAp = (float*)smem_raw;                        // [256][10]
    float* colAn = colAp + 256 * 10;                        // 20480 B

    const int tid = threadIdx.x;
    const int w = tid >> 6, lane = tid & 63, q = lane >> 4, c = lane & 15;
    const int wm = w & 1, wn = w >> 1;                      // 64-row x 128-col per wave

    // decode brick: bj2 superblock sizes 2*bj2+2
    int rem = blockIdx.x, bj2 = 0;
    while (rem >= 2 * bj2 + 2) { rem -= 2 * bj2 + 2; bj2++; }
    const int bi = rem;
    const int rowBase = bi * 128, colBase = bj2 * 256;

    if (tid < 128) { sqI[tid] = sq[rowBase + tid]; tI[tid] = tgt[rowBase + tid]; }
    sqJ[tid] = sq[colBase + tid]; tJ[tid] = tgt[colBase + tid];

    const unsigned short* Ag = xb + (size_t)rowBase * D;
    const unsigned short* Bg = xb + (size_t)colBase * D;

    f32x4 acc[4][8] = {};

    for (int k0 = 0; k0 < D; k0 += 64) {
        // A: 1024 16B chunks, B: 2048 chunks; 12 per thread. XOR source-swizzle.
        #pragma unroll
        for (int s = 0; s < 4; s++) {
            int p = s * 256 + tid;
            int r = p >> 3, kc = (p & 7) ^ (r & 7);
            gload_lds16(Ag + (size_t)r * D + k0 + kc * 8, Asm + p * 8);
        }
        #pragma unroll
        for (int s = 0; s < 8; s++) {
            int p = s * 256 + tid;
            int r = p >> 3, kc = (p & 7) ^ (r & 7);
            gload_lds16(Bg + (size_t)r * D + k0 + kc * 8, Bsm + p * 8);
        }
        __syncthreads();
        #pragma unroll
        for (int kk = 0; kk < 64; kk += 32) {
            const int kx = ((kk >> 3) + q) ^ (c & 7);       // swizzled chunk
            bf16x8 af[4], bfr[8];
            #pragma unroll
            for (int t = 0; t < 4; t++)
                af[t] = *(const bf16x8*)(Asm + (wm * 64 + t * 16 + c) * 64 + kx * 8);
            #pragma unroll
            for (int t = 0; t < 8; t++)
                bfr[t] = *(const bf16x8*)(Bsm + (wn * 128 + t * 16 + c) * 64 + kx * 8);
            #pragma unroll
            for (int tm = 0; tm < 4; tm++)
                #pragma unroll
                for (int tn = 0; tn < 8; tn++)
                    acc[tm][tn] = __builtin_amdgcn_mfma_f32_16x16x32_bf16(
                        af[tm], bfr[tn], acc[tm][tn], 0, 0, 0);
        }
        __syncthreads();
    }

    // Epilogue. C/D layout: col = lane&15 (per tn), row = q*4 + reg (per tm).
    float sjc[8]; int tj8[8];
    #pragma unroll
    for (int tn = 0; tn < 8; tn++) {
        int col_l = wn * 128 + tn * 16 + c;
        sjc[tn] = sqJ[col_l]; tj8[tn] = tJ[col_l];
    }
    float apc[8], anc[8];
    #pragma unroll
    for (int tn = 0; tn < 8; tn++) { apc[tn] = -1e30f; anc[tn] = 1e30f; }
    #pragma unroll
    for (int tm = 0; tm < 4; tm++) {
        #pragma unroll
        for (int r = 0; r < 4; r++) {
            int row_l = wm * 64 + tm * 16 + q * 4 + r;
            float si = sqI[row_l]; int ti = tI[row_l];
            float rp = -1e30f, rn = 1e30f;
            #pragma unroll
            for (int tn = 0; tn < 8; tn++) {
                float p = acc[tm][tn][r];
                bool same = (ti == tj8[tn]);
                float rk = fmaf(-2.0f, p, sjc[tn]);         // row-side key
                float ck = fmaf(-2.0f, p, si);              // col-side key
                rp = fmaxf(rp, same ? rk : -1e30f);
                rn = fminf(rn, same ? 1e30f : rk);
                apc[tn] = fmaxf(apc[tn], same ? ck : -1e30f);
                anc[tn] = fminf(anc[tn], same ? 1e30f : ck);
            }
            redAp[row_l * 34 + wn * 16 + c] = rp;
            redAn[row_l * 34 + wn * 16 + c] = rn;
        }
    }
    __syncthreads();
    if (tid < 128) {
        float ap = -1e30f, an = 1e30f;
        #pragma unroll 8
        for (int u = 0; u < 32; u++) {
            ap = fmaxf(ap, redAp[tid * 34 + u]);
            an = fminf(an, redAn[tid * 34 + u]);
        }
        apvR[(size_t)bj2 * N + rowBase + tid] = sqI[tid] + ap;  // true d^2
        anvR[(size_t)bj2 * N + rowBase + tid] = sqI[tid] + an;
    }
    __syncthreads();                                        // row phase done
    #pragma unroll
    for (int tn = 0; tn < 8; tn++) {
        int col_l = wn * 128 + tn * 16 + c;
        colAp[col_l * 10 + wm * 4 + q] = apc[tn];
        colAn[col_l * 10 + wm * 4 + q] = anc[tn];
    }
    __syncthreads();
    {
        float ap = -1e30f, an = 1e30f;
        #pragma unroll
        for (int u = 0; u < 8; u++) {
            ap = fmaxf(ap, colAp[tid * 10 + u]);
            an = fminf(an, colAn[tid * 10 + u]);
        }
        apvC[(size_t)bi * N + colBase + tid] = sqJ[tid] + ap;
        anvC[(size_t)bi * N + colBase + tid] = sqJ[tid] + an;
    }
}

// Kernel 3: per-row final max/min over valid slots; sqrt+relu; block sums;
// last block (atomic counter) folds 32 block sums into the mean.
__global__ void reduce_kernel(const float* __restrict__ apvR,
                              const float* __restrict__ anvR,
                              const float* __restrict__ apvC,
                              const float* __restrict__ anvC,
                              float* __restrict__ bsum, int* __restrict__ cnt,
                              float* __restrict__ out) {
    int tid = threadIdx.x;
    int sb = blockIdx.x;                 // superblock: 256 rows
    int row = sb * 256 + tid;
    float ap = -1e30f, an = 1e30f;
    for (int s = sb; s < NSB; s++) {                        // row-side slots
        ap = fmaxf(ap, apvR[(size_t)s * N + row]);
        an = fminf(an, anvR[(size_t)s * N + row]);
    }
    for (int s = 0; s < 2 * sb + 2; s++) {                  // col-side slots
        ap = fmaxf(ap, apvC[(size_t)s * N + row]);
        an = fminf(an, anvC[(size_t)s * N + row]);
    }
    float dap = sqrtf(fmaxf(ap, 1e-12f));
    float dan = sqrtf(fmaxf(an, 1e-12f));
    float v = fmaxf(dap - dan + MARGIN, 0.0f);
    #pragma unroll
    for (int o = 32; o > 0; o >>= 1) v += __shfl_xor(v, o);
    __shared__ float ss[4];
    __shared__ int amLast;
    if ((tid & 63) == 0) ss[tid >> 6] = v;
    __syncthreads();
    if (tid == 0) {
        bsum[sb] = ss[0] + ss[1] + ss[2] + ss[3];
        __threadfence();
        amLast = (atomicAdd(cnt, 1) == N / 256 - 1);
    }
    __syncthreads();
    if (amLast && tid < 64) {
        __threadfence();
        float t = (tid < N / 256) ? bsum[tid] : 0.0f;
        #pragma unroll
        for (int o = 32; o > 0; o >>= 1) t += __shfl_xor(t, o);
        if (tid == 0) out[0] = t * (1.0f / (float)N);
    }
}

extern "C" void kernel_launch(void* const* d_in, const int* in_sizes, int n_in,
                              void* d_out, int out_size, void* d_ws, size_t ws_size,
                              hipStream_t stream) {
    const float* x  = (const float*)d_in[0];
    const int* tgt  = (const int*)d_in[1];
    float* out      = (float*)d_out;

    char* ws = (char*)d_ws;
    unsigned short* xb = (unsigned short*)ws;                       // 8 MB bf16 X
    float* sq   = (float*)(ws + (size_t)N * D * 2);                 // 32 KB
    float* apvR = sq + N;                                           // 1 MB [32][N]
    float* anvR = apvR + (size_t)NSB * N;                           // 1 MB
    float* apvC = anvR + (size_t)NSB * N;                           // 2 MB [64][N]
    float* anvC = apvC + (size_t)NB * N;                            // 2 MB
    float* bsum = anvC + (size_t)NB * N;                            // 128 B
    int* cnt = (int*)(bsum + 32);

    const int nbricks = NSB * (NSB + 1);                            // 1056
    prep_kernel<<<N / 4, 256, 0, stream>>>(x, xb, sq, cnt);
    gemm_kernel<<<nbricks, 256, 0, stream>>>(xb, sq, tgt, apvR, anvR, apvC, anvC);
    reduce_kernel<<<N / 256, 256, 0, stream>>>(apvR, anvR, apvC, anvC, bsum, cnt, out);
}

// Round 5
// 124.026 us; speedup vs baseline: 1.1276x; 1.1276x over previous
//
#include <hip/hip_runtime.h>

#define N 8192
#define D 512
#define NB (N / 128)          // 64 row blocks (128 rows)
#define NSB 32                // 32 col superblocks (256 cols)
#define MARGIN 0.3f

typedef __attribute__((ext_vector_type(8))) short bf16x8;   // 8 bf16 = 4 VGPRs
typedef __attribute__((ext_vector_type(4))) float f32x4;    // MFMA accumulator

// round-to-nearest-even fp32 -> bf16
__device__ __forceinline__ unsigned short f2bf(float f) {
    unsigned int u = __float_as_uint(f);
    u += 0x7fffu + ((u >> 16) & 1u);
    return (unsigned short)(u >> 16);
}

// async global->LDS, 16B per lane; LDS dest = wave-uniform base + lane*16.
__device__ __forceinline__ void gload_lds16(const void* g, void* l) {
    __builtin_amdgcn_global_load_lds(
        (const __attribute__((address_space(1))) void*)g,
        (__attribute__((address_space(3))) void*)l,
        16, 0, 0);
}

// Kernel 1: per-row fp32 sum-of-squares (exact) + bf16 cast + atomic-array init.
// apU init = 0 (bits 0), anU init = +inf (0x7f800000); counter = 0.
__global__ void prep_kernel(const float* __restrict__ x,
                            unsigned short* __restrict__ xb,
                            float* __restrict__ sq,
                            unsigned int* __restrict__ apU,
                            unsigned int* __restrict__ anU,
                            int* __restrict__ cnt) {
    if (blockIdx.x == 0 && threadIdx.x == 0) cnt[0] = 0;
    int w = threadIdx.x >> 6, lane = threadIdx.x & 63;
    int row = blockIdx.x * 4 + w;
    const float4* p = (const float4*)(x + (size_t)row * D) + lane * 2;
    float4 v0 = p[0], v1 = p[1];
    float s = v0.x * v0.x + v0.y * v0.y + v0.z * v0.z + v0.w * v0.w
            + v1.x * v1.x + v1.y * v1.y + v1.z * v1.z + v1.w * v1.w;
    bf16x8 pk;
    pk[0] = (short)f2bf(v0.x); pk[1] = (short)f2bf(v0.y);
    pk[2] = (short)f2bf(v0.z); pk[3] = (short)f2bf(v0.w);
    pk[4] = (short)f2bf(v1.x); pk[5] = (short)f2bf(v1.y);
    pk[6] = (short)f2bf(v1.z); pk[7] = (short)f2bf(v1.w);
    *(bf16x8*)(xb + (size_t)row * D + lane * 8) = pk;
    #pragma unroll
    for (int o = 32; o > 0; o >>= 1) s += __shfl_xor(s, o);
    if (lane == 0) {
        sq[row] = s;
        apU[row] = 0u;                 // max-d^2 accumulator (d^2 clamped >= 0)
        anU[row] = 0x7f800000u;        // min-d^2 accumulator (+inf)
    }
}

// Kernel 2: 128x256 brick, triangular grid (bi rowblock, bj2 col-superblock,
// brick exists iff bi <= 2*bj2+1). Per wave 64x128 = 4tm x 8tn MFMA tiles.
// Selection in d^2-space; per-row brick partials end in ONE device-scope
// uint atomicMax/Min per row (clamped d^2 >= 0 -> float order == uint order).
__global__ __launch_bounds__(256, 2)
void gemm_kernel(const unsigned short* __restrict__ xb,
                 const float* __restrict__ sq,
                 const int* __restrict__ tgt,
                 unsigned int* __restrict__ apU,
                 unsigned int* __restrict__ anU) {
    __shared__ __align__(16) char smem_raw[49152];          // A(16K)+B(32K); reused
    __shared__ float sqI[128], sqJ[256];
    __shared__ int tI[128], tJ[256];
    unsigned short* Asm = (unsigned short*)smem_raw;        // [128][64] bf16 swizzled
    unsigned short* Bsm = Asm + 128 * 64;                   // [256][64] bf16 swizzled
    float* redAp = (float*)smem_raw;                        // [128][34]
    float* redAn = redAp + 128 * 34;                        // 34816 B
    float* colAp = (float*)smem_raw;                        // [256][10]
    float* colAn = colAp + 256 * 10;                        // 20480 B

    const int tid = threadIdx.x;
    const int w = tid >> 6, lane = tid & 63, q = lane >> 4, c = lane & 15;
    const int wm = w & 1, wn = w >> 1;                      // 64-row x 128-col per wave

    // decode brick: col-superblock bj2 has 2*bj2+2 row-blocks
    int rem = blockIdx.x, bj2 = 0;
    while (rem >= 2 * bj2 + 2) { rem -= 2 * bj2 + 2; bj2++; }
    const int bi = rem;
    const int rowBase = bi * 128, colBase = bj2 * 256;

    if (tid < 128) { sqI[tid] = sq[rowBase + tid]; tI[tid] = tgt[rowBase + tid]; }
    sqJ[tid] = sq[colBase + tid]; tJ[tid] = tgt[colBase + tid];

    const unsigned short* Ag = xb + (size_t)rowBase * D;
    const unsigned short* Bg = xb + (size_t)colBase * D;

    f32x4 acc[4][8] = {};

    for (int k0 = 0; k0 < D; k0 += 64) {
        // A: 1024 16B chunks, B: 2048; 12/thread. XOR source-swizzle.
        #pragma unroll
        for (int s = 0; s < 4; s++) {
            int p = s * 256 + tid;
            int r = p >> 3, kc = (p & 7) ^ (r & 7);
            gload_lds16(Ag + (size_t)r * D + k0 + kc * 8, Asm + p * 8);
        }
        #pragma unroll
        for (int s = 0; s < 8; s++) {
            int p = s * 256 + tid;
            int r = p >> 3, kc = (p & 7) ^ (r & 7);
            gload_lds16(Bg + (size_t)r * D + k0 + kc * 8, Bsm + p * 8);
        }
        __syncthreads();
        #pragma unroll
        for (int kk = 0; kk < 64; kk += 32) {
            const int kx = ((kk >> 3) + q) ^ (c & 7);       // swizzled chunk
            bf16x8 af[4], bfr[8];
            #pragma unroll
            for (int t = 0; t < 4; t++)
                af[t] = *(const bf16x8*)(Asm + (wm * 64 + t * 16 + c) * 64 + kx * 8);
            #pragma unroll
            for (int t = 0; t < 8; t++)
                bfr[t] = *(const bf16x8*)(Bsm + (wn * 128 + t * 16 + c) * 64 + kx * 8);
            #pragma unroll
            for (int tm = 0; tm < 4; tm++)
                #pragma unroll
                for (int tn = 0; tn < 8; tn++)
                    acc[tm][tn] = __builtin_amdgcn_mfma_f32_16x16x32_bf16(
                        af[tm], bfr[tn], acc[tm][tn], 0, 0, 0);
        }
        __syncthreads();
    }

    // Epilogue. C/D layout: col = lane&15 (per tn), row = q*4 + reg (per tm).
    float sjc[8]; int tj8[8];
    #pragma unroll
    for (int tn = 0; tn < 8; tn++) {
        int col_l = wn * 128 + tn * 16 + c;
        sjc[tn] = sqJ[col_l]; tj8[tn] = tJ[col_l];
    }
    float apc[8], anc[8];
    #pragma unroll
    for (int tn = 0; tn < 8; tn++) { apc[tn] = -1e30f; anc[tn] = 1e30f; }
    #pragma unroll
    for (int tm = 0; tm < 4; tm++) {
        #pragma unroll
        for (int r = 0; r < 4; r++) {
            int row_l = wm * 64 + tm * 16 + q * 4 + r;
            float si = sqI[row_l]; int ti = tI[row_l];
            float rp = -1e30f, rn = 1e30f;
            #pragma unroll
            for (int tn = 0; tn < 8; tn++) {
                float p = acc[tm][tn][r];
                bool same = (ti == tj8[tn]);
                float rk = fmaf(-2.0f, p, sjc[tn]);         // row-side key
                float ck = fmaf(-2.0f, p, si);              // col-side key
                rp = fmaxf(rp, same ? rk : -1e30f);
                rn = fminf(rn, same ? 1e30f : rk);
                apc[tn] = fmaxf(apc[tn], same ? ck : -1e30f);
                anc[tn] = fminf(anc[tn], same ? 1e30f : ck);
            }
            redAp[row_l * 34 + wn * 16 + c] = rp;
            redAn[row_l * 34 + wn * 16 + c] = rn;
        }
    }
    __syncthreads();
    if (tid < 128) {
        float ap = -1e30f, an = 1e30f;
        #pragma unroll 8
        for (int u = 0; u < 32; u++) {
            ap = fmaxf(ap, redAp[tid * 34 + u]);
            an = fminf(an, redAn[tid * 34 + u]);
        }
        // restore true d^2, clamp >=0 so uint-bit compare == float compare
        float apd = fmaxf(sqI[tid] + ap, 0.0f);
        float and_ = fmaxf(sqI[tid] + an, 0.0f);
        atomicMax(&apU[rowBase + tid], __float_as_uint(apd));
        atomicMin(&anU[rowBase + tid], __float_as_uint(and_));
    }
    __syncthreads();                                        // row phase done
    #pragma unroll
    for (int tn = 0; tn < 8; tn++) {
        int col_l = wn * 128 + tn * 16 + c;
        colAp[col_l * 10 + wm * 4 + q] = apc[tn];
        colAn[col_l * 10 + wm * 4 + q] = anc[tn];
    }
    __syncthreads();
    {
        float ap = -1e30f, an = 1e30f;
        #pragma unroll
        for (int u = 0; u < 8; u++) {
            ap = fmaxf(ap, colAp[tid * 10 + u]);
            an = fminf(an, colAn[tid * 10 + u]);
        }
        float apd = fmaxf(sqJ[tid] + ap, 0.0f);
        float and_ = fmaxf(sqJ[tid] + an, 0.0f);
        atomicMax(&apU[colBase + tid], __float_as_uint(apd));
        atomicMin(&anU[colBase + tid], __float_as_uint(and_));
    }
}

// Kernel 3: per-row ap/an are final in apU/anU. sqrt + relu + sum; last block
// (atomic counter) folds the 32 block sums into the mean.
__global__ void reduce_kernel(const unsigned int* __restrict__ apU,
                              const unsigned int* __restrict__ anU,
                              float* __restrict__ bsum, int* __restrict__ cnt,
                              float* __restrict__ out) {
    int tid = threadIdx.x;
    int row = blockIdx.x * 256 + tid;
    float ap = __uint_as_float(apU[row]);
    float an = __uint_as_float(anU[row]);
    float dap = sqrtf(fmaxf(ap, 1e-12f));
    float dan = sqrtf(fmaxf(an, 1e-12f));
    float v = fmaxf(dap - dan + MARGIN, 0.0f);
    #pragma unroll
    for (int o = 32; o > 0; o >>= 1) v += __shfl_xor(v, o);
    __shared__ float ss[4];
    __shared__ int amLast;
    if ((tid & 63) == 0) ss[tid >> 6] = v;
    __syncthreads();
    if (tid == 0) {
        bsum[blockIdx.x] = ss[0] + ss[1] + ss[2] + ss[3];
        __threadfence();
        amLast = (atomicAdd(cnt, 1) == N / 256 - 1);
    }
    __syncthreads();
    if (amLast && tid < 64) {
        __threadfence();
        float t = (tid < N / 256) ? bsum[tid] : 0.0f;
        #pragma unroll
        for (int o = 32; o > 0; o >>= 1) t += __shfl_xor(t, o);
        if (tid == 0) out[0] = t * (1.0f / (float)N);
    }
}

extern "C" void kernel_launch(void* const* d_in, const int* in_sizes, int n_in,
                              void* d_out, int out_size, void* d_ws, size_t ws_size,
                              hipStream_t stream) {
    const float* x  = (const float*)d_in[0];
    const int* tgt  = (const int*)d_in[1];
    float* out      = (float*)d_out;

    char* ws = (char*)d_ws;
    unsigned short* xb = (unsigned short*)ws;                       // 8 MB bf16 X
    float* sq   = (float*)(ws + (size_t)N * D * 2);                 // 32 KB
    unsigned int* apU = (unsigned int*)(sq + N);                    // 32 KB
    unsigned int* anU = apU + N;                                    // 32 KB
    float* bsum = (float*)(anU + N);                                // 128 B
    int* cnt = (int*)(bsum + 32);

    const int nbricks = NSB * (NSB + 1);                            // 1056
    prep_kernel<<<N / 4, 256, 0, stream>>>(x, xb, sq, apU, anU, cnt);
    gemm_kernel<<<nbricks, 256, 0, stream>>>(xb, sq, tgt, apU, anU);
    reduce_kernel<<<N / 256, 256, 0, stream>>>(apU, anU, bsum, cnt, out);
}